// Round 1
// baseline (18701.218 us; speedup 1.0000x reference)
//
#include <hip/hip_runtime.h>
#include <math.h>

#define B_ 1024
#define T_ 128
#define H_ 2048
#define C_ 10

// Ping-pong hidden-state buffers (16 MB). Static device memory: no hipMalloc,
// no reliance on ws_size, rewritten fully every call (t=0 kernel writes all of
// buf 0 without reading it).
__device__ float g_h[2][(size_t)B_ * H_];

// t = 0: h1 = tanh(x[:,0] * W_hx + b_h)   (h0 == 0, so no matmul)
__global__ __launch_bounds__(256) void rnn_init(const float* __restrict__ x,
                                                const float* __restrict__ Whx,
                                                const float* __restrict__ bh) {
    int idx = blockIdx.x * 256 + threadIdx.x;   // 0 .. B_*H_-1
    int b = idx >> 11;                          // / H_
    int j = idx & (H_ - 1);
    g_h[0][idx] = tanhf(fmaf(x[(size_t)b * T_], Whx[j], bh[j]));
}

// One RNN step: hn = tanh(x[:,t]*W_hx + h @ W_hh + b_h)
// Block tile 64 (M) x 128 (N), BK=16, 256 threads, 4x8 per thread.
__global__ __launch_bounds__(256) void rnn_step(const float* __restrict__ Whh,
                                                const float* __restrict__ Whx,
                                                const float* __restrict__ bhp,
                                                const float* __restrict__ x,
                                                int t, int sb, int db) {
    __shared__ float As[2][16][68];    // K-major, +4 pad: transposed-store 2-way max
    __shared__ float Bs[2][16][128];

    const float* __restrict__ h  = g_h[sb];
    float*       __restrict__ hn = g_h[db];

    const int tid = threadIdx.x;
    const int tx  = tid & 15;          // n-dim thread coord (16)
    const int ty  = tid >> 4;          // m-dim thread coord (16)
    const int bm  = blockIdx.y;        // 0..15  (rows of 64)
    const int bn  = blockIdx.x;        // 0..15  (cols of 128)
    const int row0 = bm * 64 + ty * 4;
    const int col0 = bn * 128 + tx * 4;   // cols col0..col0+3 and col0+64..+67

    // A loader: 64x16 tile, one float4/thread
    const int ar  = tid >> 2;          // 0..63  (row in tile)
    const int ac4 = tid & 3;           // 0..3   (k-vec)
    // B loader: 16x128 tile, two float4/thread
    const int br  = tid >> 5;          // 0..7   (k row; second vec at +8)
    const int bc4 = tid & 31;          // 0..31  (col vec)

    float acc[4][8];
#pragma unroll
    for (int i = 0; i < 4; ++i)
#pragma unroll
        for (int j = 0; j < 8; ++j) acc[i][j] = 0.f;

    float4 aReg, bReg0, bReg1;
    // ---- stage 0 ----
    {
        const float* Ap = h + (size_t)(bm * 64 + ar) * H_ + ac4 * 4;
        aReg = *(const float4*)Ap;
        const float* Bp = Whh + (size_t)br * H_ + bn * 128 + bc4 * 4;
        bReg0 = *(const float4*)Bp;
        bReg1 = *(const float4*)(Bp + 8 * H_);
    }
    As[0][ac4 * 4 + 0][ar] = aReg.x;
    As[0][ac4 * 4 + 1][ar] = aReg.y;
    As[0][ac4 * 4 + 2][ar] = aReg.z;
    As[0][ac4 * 4 + 3][ar] = aReg.w;
    *(float4*)&Bs[0][br][bc4 * 4]     = bReg0;
    *(float4*)&Bs[0][br + 8][bc4 * 4] = bReg1;
    __syncthreads();

    for (int k0 = 0; k0 < H_; k0 += 16) {
        const int buf  = (k0 >> 4) & 1;
        const bool more = (k0 + 16) < H_;
        if (more) {   // prefetch next tile into registers
            const float* Ap = h + (size_t)(bm * 64 + ar) * H_ + (k0 + 16) + ac4 * 4;
            aReg = *(const float4*)Ap;
            const float* Bp = Whh + (size_t)(k0 + 16 + br) * H_ + bn * 128 + bc4 * 4;
            bReg0 = *(const float4*)Bp;
            bReg1 = *(const float4*)(Bp + 8 * H_);
        }
        const float(*__restrict__ Asb)[68]  = As[buf];
        const float(*__restrict__ Bsb)[128] = Bs[buf];
#pragma unroll
        for (int kk = 0; kk < 16; ++kk) {
            float4 a  = *(const float4*)&Asb[kk][ty * 4];
            float4 b0 = *(const float4*)&Bsb[kk][tx * 4];
            float4 b1 = *(const float4*)&Bsb[kk][tx * 4 + 64];
            float av[4] = {a.x, a.y, a.z, a.w};
            float bv[8] = {b0.x, b0.y, b0.z, b0.w, b1.x, b1.y, b1.z, b1.w};
#pragma unroll
            for (int i = 0; i < 4; ++i)
#pragma unroll
                for (int j = 0; j < 8; ++j)
                    acc[i][j] = fmaf(av[i], bv[j], acc[i][j]);
        }
        if (more) {
            const int nb = buf ^ 1;
            As[nb][ac4 * 4 + 0][ar] = aReg.x;
            As[nb][ac4 * 4 + 1][ar] = aReg.y;
            As[nb][ac4 * 4 + 2][ar] = aReg.z;
            As[nb][ac4 * 4 + 3][ar] = aReg.w;
            *(float4*)&Bs[nb][br][bc4 * 4]     = bReg0;
            *(float4*)&Bs[nb][br + 8][bc4 * 4] = bReg1;
        }
        __syncthreads();
    }

    // epilogue: + x_t * W_hx + b_h, tanh, store
    float xv[4];
#pragma unroll
    for (int i = 0; i < 4; ++i) xv[i] = x[(size_t)(row0 + i) * T_ + t];
    float wv[8], bv2[8];
#pragma unroll
    for (int j = 0; j < 4; ++j) {
        wv[j]      = Whx[col0 + j];
        wv[j + 4]  = Whx[col0 + 64 + j];
        bv2[j]     = bhp[col0 + j];
        bv2[j + 4] = bhp[col0 + 64 + j];
    }
#pragma unroll
    for (int i = 0; i < 4; ++i) {
        float r[8];
#pragma unroll
        for (int j = 0; j < 8; ++j)
            r[j] = tanhf(acc[i][j] + xv[i] * wv[j] + bv2[j]);
        float* dst = hn + (size_t)(row0 + i) * H_ + col0;
        *(float4*)dst        = make_float4(r[0], r[1], r[2], r[3]);
        *(float4*)(dst + 64) = make_float4(r[4], r[5], r[6], r[7]);
    }
}

// p = h_T @ W_ph + b_p : one wave per batch row, shuffle-reduce.
__global__ __launch_bounds__(64) void rnn_proj(const float* __restrict__ Wph,
                                               const float* __restrict__ bp,
                                               float* __restrict__ out, int sb) {
    const int b = blockIdx.x;
    const int l = threadIdx.x;
    const float* h = g_h[sb] + (size_t)b * H_;
    float acc[C_];
#pragma unroll
    for (int c = 0; c < C_; ++c) acc[c] = 0.f;
    for (int k = l; k < H_; k += 64) {
        float hv = h[k];
#pragma unroll
        for (int c = 0; c < C_; ++c)
            acc[c] = fmaf(hv, Wph[k * C_ + c], acc[c]);
    }
#pragma unroll
    for (int off = 32; off > 0; off >>= 1) {
#pragma unroll
        for (int c = 0; c < C_; ++c) acc[c] += __shfl_down(acc[c], off);
    }
    if (l == 0) {
#pragma unroll
        for (int c = 0; c < C_; ++c) out[b * C_ + c] = acc[c] + bp[c];
    }
}

extern "C" void kernel_launch(void* const* d_in, const int* in_sizes, int n_in,
                              void* d_out, int out_size, void* d_ws, size_t ws_size,
                              hipStream_t stream) {
    const float* x   = (const float*)d_in[0];   // [1024,128]
    const float* Whx = (const float*)d_in[1];   // [1,2048]
    const float* Whh = (const float*)d_in[2];   // [2048,2048]
    const float* bh  = (const float*)d_in[3];   // [2048]
    const float* Wph = (const float*)d_in[4];   // [2048,10]
    const float* bp  = (const float*)d_in[5];   // [1,10]
    float* out = (float*)d_out;                 // [1024,10]

    // t = 0 (h0 == 0)
    rnn_init<<<(B_ * H_) / 256, 256, 0, stream>>>(x, Whx, bh);

    int src = 0;
    dim3 grid(16, 16);   // x: N tiles (2048/128), y: M tiles (1024/64)
    for (int t = 1; t < T_; ++t) {
        rnn_step<<<grid, 256, 0, stream>>>(Whh, Whx, bh, x, t, src, 1 - src);
        src = 1 - src;
    }
    rnn_proj<<<B_, 64, 0, stream>>>(Wph, bp, out, src);
}

// Round 2
// 4884.815 us; speedup vs baseline: 3.8284x; 3.8284x over previous
//
#include <hip/hip_runtime.h>
#include <math.h>

#define B_ 1024
#define T_ 128
#define H_ 2048
#define C_ 10

typedef __bf16 bf16_t;
typedef __bf16 bf16x8 __attribute__((ext_vector_type(8)));
typedef __bf16 bf16x4 __attribute__((ext_vector_type(4)));
typedef float f32x4 __attribute__((ext_vector_type(4)));

// Static device storage (fully rewritten every call, in dependency order):
// bf16 hidden-state ping-pong (8 MB), bf16 W_hh^T (8 MB), fp32 split-K partials (16 MB).
__device__ __align__(16) bf16_t g_hb[2][(size_t)B_ * H_];
__device__ __align__(16) bf16_t g_whhT[(size_t)H_ * H_];
__device__ __align__(16) float  g_part[2][(size_t)B_ * H_];

__device__ __forceinline__ void gload16(const bf16_t* g, bf16_t* l) {
    __builtin_amdgcn_global_load_lds(
        (const __attribute__((address_space(1))) void*)g,
        (__attribute__((address_space(3))) void*)l, 16, 0, 0);
}

// One-time: W_hhT[n][k] = bf16(W_hh[k][n]) — B operand must be K-contiguous.
__global__ __launch_bounds__(256) void prep_whhT(const float* __restrict__ Whh) {
    __shared__ float tile[32][33];
    const int i  = threadIdx.x >> 3;        // 0..31
    const int j4 = (threadIdx.x & 7) * 4;   // 0..28
    const int r0 = blockIdx.y * 32;         // k block (input rows)
    const int c0 = blockIdx.x * 32;         // n block (input cols)
    f32x4 v = *(const f32x4*)(Whh + (size_t)(r0 + i) * H_ + c0 + j4);
    tile[i][j4 + 0] = v[0]; tile[i][j4 + 1] = v[1];
    tile[i][j4 + 2] = v[2]; tile[i][j4 + 3] = v[3];
    __syncthreads();
    bf16x4 o;
#pragma unroll
    for (int r = 0; r < 4; ++r) o[r] = (bf16_t)tile[j4 + r][i];
    *(bf16x4*)&g_whhT[(size_t)(c0 + i) * H_ + r0 + j4] = o;
}

// t = 0: h = tanh(x[:,0]*W_hx + b_h)  (h0 == 0) -> bf16
__global__ __launch_bounds__(256) void rnn_init(const float* __restrict__ x,
                                                const float* __restrict__ Whx,
                                                const float* __restrict__ bh) {
    const int gid = blockIdx.x * 256 + threadIdx.x;   // each does 4 cols
    const int row = gid >> 9;
    const int col = (gid & 511) << 2;
    const float xv = x[(size_t)row * T_];
    f32x4 w = *(const f32x4*)&Whx[col];
    f32x4 b = *(const f32x4*)&bh[col];
    bf16x4 o;
#pragma unroll
    for (int j = 0; j < 4; ++j) o[j] = (bf16_t)tanhf(fmaf(xv, w[j], b[j]));
    *(bf16x4*)&g_hb[0][(size_t)row * H_ + col] = o;
}

// Split-K bf16 MFMA GEMM: g_part[kz] = h[sb] @ W_hh  (K half per kz).
// 128x128 block tile, 4 waves x (64x64), BK=32, LDS double-buffered,
// one barrier per iteration, staging overlapped with MFMA.
__global__ __launch_bounds__(256) void rnn_gemm(int sb) {
    __shared__ __align__(16) bf16_t As[2][128 * 32];
    __shared__ __align__(16) bf16_t Bs[2][128 * 32];

    const int tid  = threadIdx.x;
    const int lane = tid & 63;
    const int wave = tid >> 6;
    const int bm = blockIdx.y, bn = blockIdx.x, kz = blockIdx.z;
    const int wm = (wave & 1) * 64, wn = (wave >> 1) * 64;
    const int fr = lane & 15, fq = lane >> 4;

    const bf16_t* __restrict__ A = g_hb[sb];
    const int srow = tid >> 2;              // 0..63
    const int scol = (tid & 3) * 8;         // k chunk within BK
    const bf16_t* ga = A       + (size_t)(bm * 128 + srow) * H_ + kz * 1024 + scol;
    const bf16_t* gb = g_whhT  + (size_t)(bn * 128 + srow) * H_ + kz * 1024 + scol;

    // stage buffer 0
    gload16(ga,            &As[0][tid * 8]);
    gload16(ga + 64 * H_,  &As[0][(tid + 256) * 8]);
    gload16(gb,            &Bs[0][tid * 8]);
    gload16(gb + 64 * H_,  &Bs[0][(tid + 256) * 8]);

    f32x4 acc[4][4];
#pragma unroll
    for (int i = 0; i < 4; ++i)
#pragma unroll
        for (int j = 0; j < 4; ++j) acc[i][j] = (f32x4)(0.f);

    int buf = 0;
    for (int it = 0; it < 32; ++it) {
        __syncthreads();                    // drains staging of `buf`
        if (it + 1 < 32) {                  // async-stage next tile into buf^1
            ga += 32; gb += 32;
            const int nb = buf ^ 1;
            gload16(ga,            &As[nb][tid * 8]);
            gload16(ga + 64 * H_,  &As[nb][(tid + 256) * 8]);
            gload16(gb,            &Bs[nb][tid * 8]);
            gload16(gb + 64 * H_,  &Bs[nb][(tid + 256) * 8]);
        }
        bf16x8 af[4], bfv[4];
#pragma unroll
        for (int i = 0; i < 4; ++i) {
            af[i]  = *(const bf16x8*)&As[buf][(wm + i * 16 + fr) * 32 + fq * 8];
            bfv[i] = *(const bf16x8*)&Bs[buf][(wn + i * 16 + fr) * 32 + fq * 8];
        }
#pragma unroll
        for (int i = 0; i < 4; ++i)
#pragma unroll
            for (int j = 0; j < 4; ++j)
                acc[i][j] = __builtin_amdgcn_mfma_f32_16x16x32_bf16(
                    af[i], bfv[j], acc[i][j], 0, 0, 0);
        buf ^= 1;
    }

    float* __restrict__ P = g_part[kz];
#pragma unroll
    for (int i = 0; i < 4; ++i) {
        const int row0 = bm * 128 + wm + i * 16 + fq * 4;
#pragma unroll
        for (int j = 0; j < 4; ++j) {
            const int col = bn * 128 + wn + j * 16 + fr;
#pragma unroll
            for (int r = 0; r < 4; ++r)
                P[(size_t)(row0 + r) * H_ + col] = acc[i][j][r];
        }
    }
}

// hn[db] = tanh(part0 + part1 + x[:,t]*W_hx + b_h) -> bf16
__global__ __launch_bounds__(256) void rnn_epi(const float* __restrict__ x,
                                               const float* __restrict__ Whx,
                                               const float* __restrict__ bh,
                                               int t, int db) {
    const int gid = blockIdx.x * 256 + threadIdx.x;
    const int row = gid >> 9;
    const int col = (gid & 511) << 2;
    const size_t off = (size_t)row * H_ + col;
    f32x4 p0 = *(const f32x4*)&g_part[0][off];
    f32x4 p1 = *(const f32x4*)&g_part[1][off];
    const float xv = x[(size_t)row * T_ + t];
    f32x4 w = *(const f32x4*)&Whx[col];
    f32x4 b = *(const f32x4*)&bh[col];
    bf16x4 o;
#pragma unroll
    for (int j = 0; j < 4; ++j)
        o[j] = (bf16_t)tanhf(p0[j] + p1[j] + xv * w[j] + b[j]);
    *(bf16x4*)&g_hb[db][off] = o;
}

// p = h_T @ W_ph + b_p : one wave per batch row, fp32 accumulate.
__global__ __launch_bounds__(64) void rnn_proj(const float* __restrict__ Wph,
                                               const float* __restrict__ bp,
                                               float* __restrict__ out, int sb) {
    const int b = blockIdx.x;
    const int l = threadIdx.x;
    const bf16_t* h = g_hb[sb] + (size_t)b * H_;
    float acc[C_];
#pragma unroll
    for (int c = 0; c < C_; ++c) acc[c] = 0.f;
    for (int k = l; k < H_; k += 64) {
        const float hv = (float)h[k];
#pragma unroll
        for (int c = 0; c < C_; ++c)
            acc[c] = fmaf(hv, Wph[k * C_ + c], acc[c]);
    }
#pragma unroll
    for (int off = 32; off > 0; off >>= 1)
#pragma unroll
        for (int c = 0; c < C_; ++c) acc[c] += __shfl_down(acc[c], off);
    if (l == 0) {
#pragma unroll
        for (int c = 0; c < C_; ++c) out[b * C_ + c] = acc[c] + bp[c];
    }
}

extern "C" void kernel_launch(void* const* d_in, const int* in_sizes, int n_in,
                              void* d_out, int out_size, void* d_ws, size_t ws_size,
                              hipStream_t stream) {
    const float* x   = (const float*)d_in[0];   // [1024,128]
    const float* Whx = (const float*)d_in[1];   // [1,2048]
    const float* Whh = (const float*)d_in[2];   // [2048,2048]
    const float* bh  = (const float*)d_in[3];   // [2048]
    const float* Wph = (const float*)d_in[4];   // [2048,10]
    const float* bp  = (const float*)d_in[5];   // [1,10]
    float* out = (float*)d_out;                 // [1024,10]

    prep_whhT<<<dim3(64, 64), 256, 0, stream>>>(Whh);
    rnn_init<<<(B_ * H_ / 4) / 256, 256, 0, stream>>>(x, Whx, bh);

    int src = 0;
    for (int t = 1; t < T_; ++t) {
        rnn_gemm<<<dim3(16, 8, 2), 256, 0, stream>>>(src);
        rnn_epi<<<(B_ * H_ / 4) / 256, 256, 0, stream>>>(x, Whx, bh, t, 1 - src);
        src = 1 - src;
    }
    rnn_proj<<<B_, 64, 0, stream>>>(Wph, bp, out, src);
}